// Round 1
// baseline (253.151 us; speedup 1.0000x reference)
//
#include <hip/hip_runtime.h>

// VQ codebook search, fp32 baseline.
// latents: [32, 64, 64, 64] = [b, d, h, w] fp32
// emb:     [512, 64] fp32
// out:     [32, 64, 64, 64] quantized (b,d,h,w) fp32, then 1 float vq_loss
//
// ws layout (floats): ws[0] = loss accumulator, ws[16 .. 16+512) = ||e_k||^2

constexpr int K = 512;
constexpr int D = 64;
constexpr int HW = 4096;               // 64*64
constexpr int NPIX = 32 * HW;          // 131072 pixels
constexpr long long NELEM = (long long)NPIX * D;  // 8388608 output elems

__global__ __launch_bounds__(512) void vq_prep(const float* __restrict__ emb,
                                               float* __restrict__ ws) {
    int k = threadIdx.x;               // one thread per codebook row
    if (k == 0) ws[0] = 0.0f;          // zero loss accumulator every call
    const float4* row = reinterpret_cast<const float4*>(emb + k * D);
    float s0 = 0.f, s1 = 0.f, s2 = 0.f, s3 = 0.f;
    #pragma unroll
    for (int i = 0; i < D / 4; ++i) {
        float4 v = row[i];
        s0 = fmaf(v.x, v.x, s0);
        s1 = fmaf(v.y, v.y, s1);
        s2 = fmaf(v.z, v.z, s2);
        s3 = fmaf(v.w, v.w, s3);
    }
    ws[16 + k] = (s0 + s1) + (s2 + s3);
}

__global__ __launch_bounds__(256) void vq_main(const float* __restrict__ latents,
                                               const float* __restrict__ emb,
                                               const float* __restrict__ e2,
                                               float* __restrict__ out,
                                               float* __restrict__ loss_acc) {
    const int p  = blockIdx.x * 256 + threadIdx.x;  // pixel id = b*4096 + h*64 + w
    const int b  = p >> 12;
    const int hw = p & 4095;
    const float* __restrict__ xbase = latents + (size_t)(b * D) * HW + hw;

    // Load this pixel's 64-dim vector; each unrolled load is a coalesced
    // 256B wave transaction (lanes are consecutive hw).
    float x[D];
    #pragma unroll
    for (int d = 0; d < D; ++d) x[d] = xbase[(size_t)d * HW];

    // Scan codebook: score_k = ||e_k||^2 - 2 x.e_k  (||x||^2 is argmin-invariant).
    // e rows are wave-uniform -> s_load into SGPRs; inner loop is v_fma_f32.
    float best = 3.4e38f;
    int bestk = 0;
    for (int k = 0; k < K; ++k) {
        const float* __restrict__ e = emb + k * D;
        float a0 = 0.f, a1 = 0.f, a2 = 0.f, a3 = 0.f;
        #pragma unroll
        for (int d = 0; d < D; d += 4) {
            a0 = fmaf(x[d + 0], e[d + 0], a0);
            a1 = fmaf(x[d + 1], e[d + 1], a1);
            a2 = fmaf(x[d + 2], e[d + 2], a2);
            a3 = fmaf(x[d + 3], e[d + 3], a3);
        }
        float dot = (a0 + a1) + (a2 + a3);
        float score = fmaf(-2.0f, dot, e2[k]);
        if (score < best) { best = score; bestk = k; }  // strict < => first min (jnp.argmin tie-break)
    }

    // Gather chosen code (per-lane row, L2-resident), write output in
    // [b,d,h,w] layout (coalesced per-d), accumulate (q-x)^2.
    const float4* __restrict__ eq = reinterpret_cast<const float4*>(emb + bestk * D);
    float* __restrict__ obase = out + (size_t)(b * D) * HW + hw;
    float l0 = 0.f, l1 = 0.f;
    #pragma unroll
    for (int i = 0; i < D / 4; ++i) {
        float4 q = eq[i];
        int d = 4 * i;
        float f0 = q.x - x[d + 0];
        float f1 = q.y - x[d + 1];
        float f2 = q.z - x[d + 2];
        float f3 = q.w - x[d + 3];
        l0 = fmaf(f0, f0, l0);
        l1 = fmaf(f1, f1, l1);
        l0 = fmaf(f2, f2, l0);
        l1 = fmaf(f3, f3, l1);
        obase[(size_t)(d + 0) * HW] = q.x;
        obase[(size_t)(d + 1) * HW] = q.y;
        obase[(size_t)(d + 2) * HW] = q.z;
        obase[(size_t)(d + 3) * HW] = q.w;
    }
    float lsum = l0 + l1;
    #pragma unroll
    for (int off = 32; off > 0; off >>= 1) lsum += __shfl_down(lsum, off, 64);
    if ((threadIdx.x & 63) == 0) atomicAdd(loss_acc, lsum);
}

__global__ void vq_finalize(const float* __restrict__ ws, float* __restrict__ out_loss) {
    // vq_loss = commitment*0.25 + embedding*1.0; both equal mean((q-x)^2).
    out_loss[0] = 1.25f * ws[0] / (float)NELEM;
}

extern "C" void kernel_launch(void* const* d_in, const int* in_sizes, int n_in,
                              void* d_out, int out_size, void* d_ws, size_t ws_size,
                              hipStream_t stream) {
    const float* latents = (const float*)d_in[0];
    const float* emb     = (const float*)d_in[1];
    float* out = (float*)d_out;
    float* ws  = (float*)d_ws;

    vq_prep<<<1, 512, 0, stream>>>(emb, ws);
    vq_main<<<NPIX / 256, 256, 0, stream>>>(latents, emb, ws + 16, out, ws);
    vq_finalize<<<1, 1, 0, stream>>>(ws, out + NELEM);
}

// Round 2
// 191.191 us; speedup vs baseline: 1.3241x; 1.3241x over previous
//
#include <hip/hip_runtime.h>

// VQ codebook search via bf16 MFMA.
// latents: [32, 64, 64, 64] = [b, d, h, w] fp32
// emb:     [512, 64] fp32
// out:     8388608 floats quantized (b,d,h,w) + 1 float vq_loss
//
// scores[n,k] = ||e_k||^2 - 2 x_n.e_k  (||x||^2 argmin-invariant)
// Computed as MFMA:  D = A·B + C,  A = bf16(-2E) tile [16 codes x 32 d],
// B = bf16(X) tile [32 d x 16 pixels], C = e2 broadcast.  D[m][n]: m=code, n=pixel.
//
// ws layout: ws[0] = loss acc; ws[16..528) = e2[512]; ws+544 = ebf (512x64 bf16, 64KB)

typedef short  short8v __attribute__((ext_vector_type(8)));
typedef float  f32x4   __attribute__((ext_vector_type(4)));

constexpr int K = 512;
constexpr int D = 64;
constexpr int HW = 4096;
constexpr int NPIX = 32 * HW;
constexpr long long NELEM = (long long)NPIX * D;

__device__ inline unsigned short f2bf(float f) {   // RNE float->bf16 bits
    unsigned int u = __builtin_bit_cast(unsigned int, f);
    u += 0x7fffu + ((u >> 16) & 1u);
    return (unsigned short)(u >> 16);
}

// ---- prep: e2[k] = ||e_k||^2 (fp32); ebf = bf16(-2*emb). 32 blocks x 256.
__global__ __launch_bounds__(256) void vq_prep(const float* __restrict__ emb,
                                               float* __restrict__ e2,
                                               unsigned short* __restrict__ ebf,
                                               float* __restrict__ loss_acc) {
    int tid = blockIdx.x * 256 + threadIdx.x;    // 0..8191 = code*4 + quad
    if (tid == 0) loss_acc[0] = 0.0f;            // deterministic re-zero each call
    int k = tid >> 2, quad = tid & 3;
    const float4* src = reinterpret_cast<const float4*>(emb + k * D + quad * 16);
    unsigned int pk[8];
    float s = 0.f;
    #pragma unroll
    for (int i = 0; i < 4; ++i) {
        float4 v = src[i];
        s = fmaf(v.x, v.x, fmaf(v.y, v.y, fmaf(v.z, v.z, fmaf(v.w, v.w, s))));
        pk[2*i]   = (unsigned int)f2bf(-2.f * v.x) | ((unsigned int)f2bf(-2.f * v.y) << 16);
        pk[2*i+1] = (unsigned int)f2bf(-2.f * v.z) | ((unsigned int)f2bf(-2.f * v.w) << 16);
    }
    s += __shfl_xor(s, 1, 64);                   // reduce across the 4 quads of a row
    s += __shfl_xor(s, 2, 64);
    if (quad == 0) e2[k] = s;
    unsigned int* dst = reinterpret_cast<unsigned int*>(ebf + k * D + quad * 16);
    #pragma unroll
    for (int i = 0; i < 8; ++i) dst[i] = pk[i];
}

// ---- main: 2048 blocks x 256 threads, 64 pixels per block.
__global__ __launch_bounds__(256) void vq_main(const float* __restrict__ latents,
                                               const float* __restrict__ emb,
                                               const float* __restrict__ e2,
                                               const unsigned short* __restrict__ ebf,
                                               float* __restrict__ out,
                                               float* __restrict__ loss_acc) {
    __shared__ float          xf32[D][64];       // [d][p] fp32, conflict-free both ways
    __shared__ unsigned short xbf[64 * D];       // [p][d] bf16, byte-XOR swizzled
    __shared__ float          e2s[K];
    __shared__ int            inds[64];

    const int lane = threadIdx.x & 63;
    const int w    = threadIdx.x >> 6;           // wave id 0..3
    const int b    = blockIdx.x >> 6;            // 64 px/block, 4096 px per b
    const int hw0  = (blockIdx.x & 63) * 64;

    // e2 -> LDS
    e2s[threadIdx.x]       = e2[threadIdx.x];
    e2s[threadIdx.x + 256] = e2[threadIdx.x + 256];

    // Stage X-tile: 64 pixels x 64 dims. Lane = pixel (coalesced 256B per load).
    // Wave w covers even d = 2w + 8i, plus d+1.
    const float* __restrict__ xb = latents + (size_t)b * D * HW + hw0 + lane;
    char* xbf_c = reinterpret_cast<char*>(xbf);
    const int psw = (lane & 7) << 4;             // 16B-granular XOR swizzle
    #pragma unroll
    for (int i = 0; i < 8; ++i) {
        int d = 2 * w + 8 * i;
        float f0 = xb[(size_t)d * HW];
        float f1 = xb[(size_t)(d + 1) * HW];
        xf32[d][lane]     = f0;
        xf32[d + 1][lane] = f1;
        unsigned int pk = (unsigned int)f2bf(f0) | ((unsigned int)f2bf(f1) << 16);
        *reinterpret_cast<unsigned int*>(xbf_c + ((lane * 128 + d * 2) ^ psw)) = pk;
    }
    __syncthreads();

    // B-fragments (one per K-half), same for all 32 code-tiles.
    // B layout: col = pixel = lane&15, k = (lane>>4)*8 + j (contiguous 8 bf16).
    const int P = w * 16 + (lane & 15);          // this lane's pixel (block-local)
    const int g = lane >> 4;                     // 0..3
    const int Psw = (P & 7) << 4;
    short8v b0 = *reinterpret_cast<const short8v*>(xbf_c + ((P * 128 + g * 16)      ^ Psw));
    short8v b1 = *reinterpret_cast<const short8v*>(xbf_c + ((P * 128 + g * 16 + 64) ^ Psw));

    // A base: row = code = lane&15 within tile, k-group = g.
    const char* ea = reinterpret_cast<const char*>(ebf) + (lane & 15) * 128 + g * 16;

    float best = 3.4e38f;
    int bestk = 0;
    short8v a0 = *reinterpret_cast<const short8v*>(ea);
    short8v a1 = *reinterpret_cast<const short8v*>(ea + 64);
    #pragma unroll 4
    for (int t = 0; t < 32; ++t) {
        short8v na0, na1;
        if (t < 31) {                            // prefetch next tile's A
            na0 = *reinterpret_cast<const short8v*>(ea + (t + 1) * 2048);
            na1 = *reinterpret_cast<const short8v*>(ea + (t + 1) * 2048 + 64);
        }
        float4 ev = *reinterpret_cast<const float4*>(&e2s[t * 16 + g * 4]);
        f32x4 c = {ev.x, ev.y, ev.z, ev.w};      // C-in = e2 => D = score
        c = __builtin_amdgcn_mfma_f32_16x16x32_bf16(a0, b0, c, 0, 0, 0);
        c = __builtin_amdgcn_mfma_f32_16x16x32_bf16(a1, b1, c, 0, 0, 0);
        #pragma unroll
        for (int r = 0; r < 4; ++r) {            // code = t*16 + g*4 + r (ascending)
            float s = c[r];
            if (s < best) { best = s; bestk = t * 16 + g * 4 + r; }
        }
        a0 = na0; a1 = na1;
    }

    // Combine the 4 lanes (g=0..3) sharing pixel P; tie -> lower index (jnp.argmin).
    #pragma unroll
    for (int off = 16; off < 64; off <<= 1) {
        float ob = __shfl_xor(best, off, 64);
        int   ok = __shfl_xor(bestk, off, 64);
        if (ob < best || (ob == best && ok < bestk)) { best = ob; bestk = ok; }
    }
    if (g == 0) inds[P] = bestk;
    __syncthreads();

    // Output + loss: thread handles pixel p, d in [dq*16, dq*16+16).
    const int p  = threadIdx.x & 63;
    const int dq = threadIdx.x >> 6;
    const int ind = inds[p];
    const float4* __restrict__ q4 = reinterpret_cast<const float4*>(emb + ind * D + dq * 16);
    float* __restrict__ ob = out + (size_t)b * D * HW + hw0 + p;
    float lsum = 0.f;
    #pragma unroll
    for (int i = 0; i < 4; ++i) {
        float4 q = q4[i];
        int d = dq * 16 + 4 * i;
        float f0 = q.x - xf32[d + 0][p];
        float f1 = q.y - xf32[d + 1][p];
        float f2 = q.z - xf32[d + 2][p];
        float f3 = q.w - xf32[d + 3][p];
        lsum = fmaf(f0, f0, lsum); lsum = fmaf(f1, f1, lsum);
        lsum = fmaf(f2, f2, lsum); lsum = fmaf(f3, f3, lsum);
        ob[(size_t)(d + 0) * HW] = q.x;
        ob[(size_t)(d + 1) * HW] = q.y;
        ob[(size_t)(d + 2) * HW] = q.z;
        ob[(size_t)(d + 3) * HW] = q.w;
    }
    #pragma unroll
    for (int off = 32; off > 0; off >>= 1) lsum += __shfl_down(lsum, off, 64);
    if (lane == 0) atomicAdd(loss_acc, lsum);
}

__global__ void vq_finalize(const float* __restrict__ ws, float* __restrict__ out_loss) {
    out_loss[0] = 1.25f * ws[0] / (float)NELEM;  // beta*commit + embed, equal values
}

extern "C" void kernel_launch(void* const* d_in, const int* in_sizes, int n_in,
                              void* d_out, int out_size, void* d_ws, size_t ws_size,
                              hipStream_t stream) {
    const float* latents = (const float*)d_in[0];
    const float* emb     = (const float*)d_in[1];
    float* out = (float*)d_out;
    float* ws  = (float*)d_ws;

    float*          e2  = ws + 16;
    unsigned short* ebf = (unsigned short*)(ws + 544);

    vq_prep<<<32, 256, 0, stream>>>(emb, e2, ebf, ws);
    vq_main<<<NPIX / 64, 256, 0, stream>>>(latents, emb, e2, ebf, out, ws);
    vq_finalize<<<1, 1, 0, stream>>>(ws, out + NELEM);
}

// Round 3
// 41.350 us; speedup vs baseline: 6.1222x; 4.6237x over previous
//
#include <hip/hip_runtime.h>

// VQ codebook search via bf16 MFMA — LDS-resident codebook version.
// latents: [32, 64, 64, 64] = [b, d, h, w] fp32
// emb:     [512, 64] fp32
// out:     8388608 floats quantized (b,d,h,w) + 1 float vq_loss
//
// score[n,k] = ||e_k||^2 - 2 x_n.e_k  (||x||^2 argmin-invariant), computed as
// MFMA 16x16x32: A = bf16(-2E) [16 codes x 32 d], B = bf16(X) [32 d x 16 px],
// C-init = e2. k-loop reads A only from LDS (XOR-swizzled, conflict-free).
//
// ws layout (floats): [0..512) per-block loss partials; [512..1024) e2;
//                     ws+1024: ebf_sw = PRE-SWIZZLED bf16(-2E), 64KB.

typedef short short8v __attribute__((ext_vector_type(8)));
typedef float f32x4   __attribute__((ext_vector_type(4)));

constexpr int K = 512;
constexpr int D = 64;
constexpr int HW = 4096;
constexpr int NPIX = 32 * HW;
constexpr long long NELEM = (long long)NPIX * D;
constexpr int PXB = 256;                 // pixels per block
constexpr int NBLK = NPIX / PXB;         // 512 blocks

__device__ inline unsigned short f2bf(float f) {   // RNE float->bf16 bits
    unsigned int u = __builtin_bit_cast(unsigned int, f);
    u += 0x7fffu + ((u >> 16) & 1u);
    return (unsigned short)(u >> 16);
}

// ---- prep: e2[k] = ||e_k||^2; ebf_sw = bf16(-2*emb) stored PRE-SWIZZLED:
// 16B chunk (k, col) lands at byte  k*128 + ((col*16) ^ ((k&7)<<4)).
__global__ __launch_bounds__(256) void vq_prep(const float* __restrict__ emb,
                                               float* __restrict__ e2,
                                               unsigned short* __restrict__ ebf) {
    int tid = blockIdx.x * 256 + threadIdx.x;    // 0..8191 = k*4 + quad
    int k = tid >> 2, quad = tid & 3;            // quad covers 16 floats = 2 chunks
    const float4* src = reinterpret_cast<const float4*>(emb + k * D + quad * 16);
    unsigned int pk[8];
    float s = 0.f;
    #pragma unroll
    for (int i = 0; i < 4; ++i) {
        float4 v = src[i];
        s = fmaf(v.x, v.x, fmaf(v.y, v.y, fmaf(v.z, v.z, fmaf(v.w, v.w, s))));
        pk[2*i]   = (unsigned int)f2bf(-2.f * v.x) | ((unsigned int)f2bf(-2.f * v.y) << 16);
        pk[2*i+1] = (unsigned int)f2bf(-2.f * v.z) | ((unsigned int)f2bf(-2.f * v.w) << 16);
    }
    s += __shfl_xor(s, 1, 64);
    s += __shfl_xor(s, 2, 64);
    if (quad == 0) e2[k] = s;
    char* base = reinterpret_cast<char*>(ebf);
    int swz = (k & 7) << 4;
    int col0 = quad * 32;                        // two 16B chunks: col0, col0+16
    *reinterpret_cast<uint4*>(base + k * 128 + ((col0)      ^ swz)) = uint4{pk[0], pk[1], pk[2], pk[3]};
    *reinterpret_cast<uint4*>(base + k * 128 + ((col0 + 16) ^ swz)) = uint4{pk[4], pk[5], pk[6], pk[7]};
}

// ---- main: 512 blocks x 512 threads; 256 px/block; codebook in LDS.
__global__ __launch_bounds__(512, 1) void vq_main(const float* __restrict__ latents,
                                                  const float* __restrict__ emb,
                                                  const float* __restrict__ e2,
                                                  const unsigned short* __restrict__ ebf_sw,
                                                  float* __restrict__ out,
                                                  float* __restrict__ partials) {
    __shared__ unsigned short elds[K * D];       // 64KB, swizzled image of ebf_sw
    __shared__ unsigned short xbf[PXB * D];      // 32KB, row=pixel, same swizzle
    __shared__ float e2s[K];                     // 2KB
    __shared__ int   inds[PXB];                  // 1KB
    __shared__ float wsum[8];

    const int t    = threadIdx.x;
    const int lane = t & 63, w = t >> 6;         // 8 waves
    const int blk  = blockIdx.x;
    const int b    = blk >> 4, hw0 = (blk & 15) * PXB;

    // ---- stage x: thread t owns pixel px, dims [dbase, dbase+32).
    const int px = t & 255;
    const int dbase = (t >> 8) * 32;
    const float* __restrict__ xg = latents + (size_t)b * D * HW + hw0 + px;
    float xv[32];
    #pragma unroll
    for (int j = 0; j < 32; ++j) xv[j] = xg[(size_t)(dbase + j) * HW];   // HBM, coalesced 256B

    // ---- stage codebook: direct global->LDS DMA, linear copy of pre-swizzled image.
    {
        const char* gsrc = reinterpret_cast<const char*>(ebf_sw);
        char* ldst = reinterpret_cast<char*>(elds);
        #pragma unroll
        for (int i = 0; i < 8; ++i) {            // wave w copies chunks [w*512, w*512+512)
            int cbase = w * 512 + i * 64;
            __builtin_amdgcn_global_load_lds(
                (const __attribute__((address_space(1))) unsigned int*)(gsrc + (size_t)(cbase + lane) * 16),
                (__attribute__((address_space(3))) unsigned int*)(ldst + (size_t)cbase * 16),
                16, 0, 0);
        }
    }
    e2s[t] = e2[t];                              // t < 512 = K

    // ---- pack x to bf16, write swizzled (row=px): 4x ds_write_b128, 2-way max.
    char* xb_c = reinterpret_cast<char*>(xbf);
    const int pswz = (px & 7) << 4;
    #pragma unroll
    for (int ch = 0; ch < 4; ++ch) {
        unsigned int pk[4];
        #pragma unroll
        for (int q = 0; q < 4; ++q) {
            int j = ch * 8 + q * 2;
            pk[q] = (unsigned int)f2bf(xv[j]) | ((unsigned int)f2bf(xv[j + 1]) << 16);
        }
        int col = dbase * 2 + ch * 16;
        *reinterpret_cast<uint4*>(xb_c + px * 128 + (col ^ pswz)) = uint4{pk[0], pk[1], pk[2], pk[3]};
    }
    __syncthreads();                             // drains global_load_lds (vmcnt) + ds_writes

    // ---- B-fragments: wave w owns pixels [w*32, w*32+32) = 2 pixel-tiles.
    const int r15 = lane & 15, g = lane >> 4;
    short8v bf[2][2];
    #pragma unroll
    for (int pt = 0; pt < 2; ++pt) {
        int P = w * 32 + pt * 16 + r15;
        int sw = (P & 7) << 4;
        bf[pt][0] = *reinterpret_cast<const short8v*>(xb_c + P * 128 + ((g * 16)      ^ sw));
        bf[pt][1] = *reinterpret_cast<const short8v*>(xb_c + P * 128 + ((g * 16 + 64) ^ sw));
    }

    // ---- k-loop: pure LDS + MFMA. A row = code (r15 within tile), cols by g.
    const char* e_c = reinterpret_cast<const char*>(elds);
    const int rswz = (r15 & 7) << 4;
    const int ca0 = r15 * 128 + ((g * 16)      ^ rswz);
    const int ca1 = r15 * 128 + ((g * 16 + 64) ^ rswz);

    float best[2][4];
    int   btt[2][4];
    #pragma unroll
    for (int pt = 0; pt < 2; ++pt)
        #pragma unroll
        for (int el = 0; el < 4; ++el) { best[pt][el] = 3.4e38f; btt[pt][el] = 0; }

    #pragma unroll 4
    for (int tt = 0; tt < 32; ++tt) {
        short8v a0 = *reinterpret_cast<const short8v*>(e_c + ca0 + tt * 2048);
        short8v a1 = *reinterpret_cast<const short8v*>(e_c + ca1 + tt * 2048);
        f32x4 einit = *reinterpret_cast<const f32x4*>(&e2s[tt * 16 + g * 4]);
        #pragma unroll
        for (int pt = 0; pt < 2; ++pt) {
            f32x4 c = einit;                     // C-in = e2 => D = score
            c = __builtin_amdgcn_mfma_f32_16x16x32_bf16(a0, bf[pt][0], c, 0, 0, 0);
            c = __builtin_amdgcn_mfma_f32_16x16x32_bf16(a1, bf[pt][1], c, 0, 0, 0);
            #pragma unroll
            for (int el = 0; el < 4; ++el) {     // ascending tt => first-min kept
                if (c[el] < best[pt][el]) { best[pt][el] = c[el]; btt[pt][el] = tt; }
            }
        }
    }

    // ---- reduce 4 el-slots (lex by code), then across g-groups, write inds.
    #pragma unroll
    for (int pt = 0; pt < 2; ++pt) {
        float bs = best[pt][0];
        int   bc = btt[pt][0] * 16 + g * 4;
        #pragma unroll
        for (int el = 1; el < 4; ++el) {
            float s = best[pt][el];
            int   cd = btt[pt][el] * 16 + g * 4 + el;
            if (s < bs || (s == bs && cd < bc)) { bs = s; bc = cd; }
        }
        #pragma unroll
        for (int off = 16; off < 64; off <<= 1) {
            float os = __shfl_xor(bs, off, 64);
            int   oc = __shfl_xor(bc, off, 64);
            if (os < bs || (os == bs && oc < bc)) { bs = os; bc = oc; }
        }
        if (g == 0) inds[w * 32 + pt * 16 + r15] = bc;
    }
    __syncthreads();

    // ---- epilogue: x still in regs; gather code (L2), write out, loss partial.
    const int ind = inds[px];
    const float4* __restrict__ q4 = reinterpret_cast<const float4*>(emb + ind * D + dbase);
    float* __restrict__ og = out + (size_t)b * D * HW + hw0 + px;
    float lsum = 0.f;
    #pragma unroll
    for (int i = 0; i < 8; ++i) {
        float4 q = q4[i];
        int j = 4 * i;
        float f0 = q.x - xv[j + 0];
        float f1 = q.y - xv[j + 1];
        float f2 = q.z - xv[j + 2];
        float f3 = q.w - xv[j + 3];
        lsum = fmaf(f0, f0, lsum); lsum = fmaf(f1, f1, lsum);
        lsum = fmaf(f2, f2, lsum); lsum = fmaf(f3, f3, lsum);
        og[(size_t)(dbase + j + 0) * HW] = q.x;
        og[(size_t)(dbase + j + 1) * HW] = q.y;
        og[(size_t)(dbase + j + 2) * HW] = q.z;
        og[(size_t)(dbase + j + 3) * HW] = q.w;
    }
    #pragma unroll
    for (int off = 32; off > 0; off >>= 1) lsum += __shfl_down(lsum, off, 64);
    if (lane == 0) wsum[w] = lsum;
    __syncthreads();
    if (t == 0) {
        float s = 0.f;
        #pragma unroll
        for (int i = 0; i < 8; ++i) s += wsum[i];
        partials[blk] = s;
    }
}

__global__ __launch_bounds__(512) void vq_finalize(const float* __restrict__ partials,
                                                   float* __restrict__ out_loss) {
    int t = threadIdx.x;
    float v = partials[t];
    #pragma unroll
    for (int off = 32; off > 0; off >>= 1) v += __shfl_down(v, off, 64);
    __shared__ float s8[8];
    if ((t & 63) == 0) s8[t >> 6] = v;
    __syncthreads();
    if (t == 0) {
        float tot = 0.f;
        #pragma unroll
        for (int i = 0; i < 8; ++i) tot += s8[i];
        out_loss[0] = 1.25f * tot / (float)NELEM;   // beta*commit + embed (equal values)
    }
}

extern "C" void kernel_launch(void* const* d_in, const int* in_sizes, int n_in,
                              void* d_out, int out_size, void* d_ws, size_t ws_size,
                              hipStream_t stream) {
    const float* latents = (const float*)d_in[0];
    const float* emb     = (const float*)d_in[1];
    float* out = (float*)d_out;
    float* ws  = (float*)d_ws;

    float*          part = ws;                    // [0..512)
    float*          e2   = ws + 512;              // [512..1024)
    unsigned short* ebf  = (unsigned short*)(ws + 1024);  // 64KB

    vq_prep<<<32, 256, 0, stream>>>(emb, e2, ebf);
    vq_main<<<NBLK, 512, 0, stream>>>(latents, emb, e2, ebf, out, part);
    vq_finalize<<<1, 512, 0, stream>>>(part, out + NELEM);
}